// Round 3
// baseline (670.882 us; speedup 1.0000x reference)
//
#include <hip/hip_runtime.h>
#include <hip/hip_bf16.h>

#define D_HID 128
#define D_OUT 100
#define BN_EPS 1e-5f

// ---------------- helpers ----------------
__device__ __forceinline__ unsigned fmap(float f) {
    unsigned u = __float_as_uint(f);
    return (u & 0x80000000u) ? ~u : (u | 0x80000000u);
}
__device__ __forceinline__ float funmap(unsigned u) {
    return __uint_as_float((u & 0x80000000u) ? (u ^ 0x80000000u) : ~u);
}
#define NEG_INF_MAPPED 0x007FFFFFu  // fmap(-inf)

// ---------------- init ----------------
__global__ __launch_bounds__(256) void init_k(int* deg, int* cursor, unsigned* pool,
                                              float* bnsum, float* bnsq, int N, int P) {
    int i = blockIdx.x * 256 + threadIdx.x;
    if (i < N) { deg[i] = 0; cursor[i] = 0; }
    if (i < P) pool[i] = NEG_INF_MAPPED;
    if (i < 128) { bnsum[i] = 0.f; bnsq[i] = 0.f; }
}

__global__ __launch_bounds__(256) void deg_k(const int* __restrict__ dst, int* deg, int E) {
    int e = blockIdx.x * 256 + threadIdx.x;
    if (e < E) atomicAdd(&deg[dst[e]], 1);
}

// ---------------- exclusive scan over deg -> off (2-level) ----------------
#define SCAN_EPB 1024  // elements per block (256 threads x 4)
__global__ __launch_bounds__(256) void scan1_k(const int* __restrict__ deg, int* __restrict__ off,
                                               int* __restrict__ btot, int N) {
    __shared__ int ts[256];
    int base = blockIdx.x * SCAN_EPB + threadIdx.x * 4;
    int v[4];
    int s = 0;
#pragma unroll
    for (int j = 0; j < 4; ++j) { int idx = base + j; v[j] = (idx < N) ? deg[idx] : 0; s += v[j]; }
    ts[threadIdx.x] = s;
    __syncthreads();
    for (int d = 1; d < 256; d <<= 1) {
        int t = (threadIdx.x >= d) ? ts[threadIdx.x - d] : 0;
        __syncthreads();
        ts[threadIdx.x] += t;
        __syncthreads();
    }
    int excl = ts[threadIdx.x] - s;
#pragma unroll
    for (int j = 0; j < 4; ++j) { int idx = base + j; if (idx < N) off[idx] = excl; excl += v[j]; }
    if (threadIdx.x == 255) btot[blockIdx.x] = ts[255];
}

__global__ __launch_bounds__(256) void scan2_k(int* btot, int nb, int* off, int N, int E) {
    __shared__ int ts[256];
    int v = (threadIdx.x < nb) ? btot[threadIdx.x] : 0;
    ts[threadIdx.x] = v;
    __syncthreads();
    for (int d = 1; d < 256; d <<= 1) {
        int t = (threadIdx.x >= d) ? ts[threadIdx.x - d] : 0;
        __syncthreads();
        ts[threadIdx.x] += t;
        __syncthreads();
    }
    if (threadIdx.x < nb) btot[threadIdx.x] = ts[threadIdx.x] - v;  // exclusive
    if (threadIdx.x == 0) off[N] = E;
}

__global__ __launch_bounds__(256) void scan3_dinv_k(int* off, const int* __restrict__ btot,
                                                    const int* __restrict__ deg,
                                                    float* __restrict__ dinv, int N) {
    int i = blockIdx.x * 256 + threadIdx.x;
    if (i < N) {
        off[i] += btot[i / SCAN_EPB];
        dinv[i] = rsqrtf((float)(1 + deg[i]));  // +1 self-loop
    }
}

__global__ __launch_bounds__(256) void fill_k(const int* __restrict__ src, const int* __restrict__ dst,
                                              const int* __restrict__ off, int* cursor,
                                              int* __restrict__ csr, int E) {
    int e = blockIdx.x * 256 + threadIdx.x;
    if (e < E) {
        int d = dst[e];
        int p = atomicAdd(&cursor[d], 1);
        csr[off[d] + p] = src[e];
    }
}

// ---------------- GEMM1: H = X @ W1  (f32, 64x128 tile) ----------------
#define BM 64
#define BK 32
__global__ __launch_bounds__(256) void gemm1_k(const float* __restrict__ X,
                                               const float* __restrict__ W,
                                               float* __restrict__ H, int N) {
    __shared__ float Xs[BK][BM];
    __shared__ float Ws[BK][128];
    int tid = threadIdx.x;
    int row0 = blockIdx.x * BM;
    int tx = tid & 31, ty = tid >> 5;
    float acc[8][4] = {};
    for (int k0 = 0; k0 < 128; k0 += BK) {
        {
            int kk = tid & 31, rb = tid >> 5;
            for (int j = 0; j < 8; ++j) {
                int r = rb + 8 * j, row = row0 + r;
                Xs[kk][r] = (row < N) ? X[(long long)row * 128 + k0 + kk] : 0.f;
            }
        }
        {
            int c = tid & 127, kb = tid >> 7;
            for (int j = 0; j < 16; ++j) {
                int kk = kb + 2 * j;
                Ws[kk][c] = W[(k0 + kk) * 128 + c];
            }
        }
        __syncthreads();
        for (int kk = 0; kk < BK; ++kk) {
            float4 w = *(const float4*)&Ws[kk][tx * 4];
            float x[8];
            *(float4*)&x[0] = *(const float4*)&Xs[kk][ty * 8];
            *(float4*)&x[4] = *(const float4*)&Xs[kk][ty * 8 + 4];
#pragma unroll
            for (int r = 0; r < 8; ++r) {
                acc[r][0] += x[r] * w.x; acc[r][1] += x[r] * w.y;
                acc[r][2] += x[r] * w.z; acc[r][3] += x[r] * w.w;
            }
        }
        __syncthreads();
    }
    for (int r = 0; r < 8; ++r) {
        int row = row0 + ty * 8 + r;
        if (row < N) *(float4*)&H[(long long)row * 128 + tx * 4] = *(float4*)&acc[r][0];
    }
}

// ---------------- agg1: X1 = Dinv(A+I)Dinv H, fused BN stats ----------------
// 32-lane groups, float4/lane: 8 independent node-chains per 256-thread block.
__global__ __launch_bounds__(256) void agg1_k(const float* __restrict__ H,
                                              const int* __restrict__ off,
                                              const int* __restrict__ csr,
                                              const float* __restrict__ dinv,
                                              float* __restrict__ X1,
                                              float* bnsum, float* bnsq,
                                              int N, int chunk) {
    int grp = blockIdx.x * 8 + (threadIdx.x >> 5);
    int lane = threadIdx.x & 31;
    int n0 = grp * chunk;
    int n1 = n0 + chunk; if (n1 > N) n1 = N;
    float bsx = 0.f, bsy = 0.f, bsz = 0.f, bsw = 0.f;
    float bqx = 0.f, bqy = 0.f, bqz = 0.f, bqw = 0.f;
    const float4* H4 = (const float4*)H;
    float4* X14 = (float4*)X1;
    if (n0 < n1) {
        int is = off[n0];
        for (int n = n0; n < n1; ++n) {
            int ie = off[n + 1];
            float dn = dinv[n];
            float w = dn * dn;
            float4 h = H4[(long long)n * 32 + lane];
            float ax = w * h.x, ay = w * h.y, az = w * h.z, aw = w * h.w;
            for (int i = is; i < ie; ++i) {
                int s = csr[i];
                float ws = dinv[s] * dn;
                float4 hs = H4[(long long)s * 32 + lane];
                ax += ws * hs.x; ay += ws * hs.y; az += ws * hs.z; aw += ws * hs.w;
            }
            is = ie;
            float4 o; o.x = ax; o.y = ay; o.z = az; o.w = aw;
            X14[(long long)n * 32 + lane] = o;
            bsx += ax; bsy += ay; bsz += az; bsw += aw;
            bqx += ax * ax; bqy += ay * ay; bqz += az * az; bqw += aw * aw;
        }
    }
    __shared__ float4 ls[256], lq[256];
    float4 s4; s4.x = bsx; s4.y = bsy; s4.z = bsz; s4.w = bsw;
    float4 q4; q4.x = bqx; q4.y = bqy; q4.z = bqz; q4.w = bqw;
    ls[threadIdx.x] = s4; lq[threadIdx.x] = q4;
    __syncthreads();
    if (threadIdx.x < 32) {
        float4 s = ls[threadIdx.x], q = lq[threadIdx.x];
#pragma unroll
        for (int j = 32; j < 256; j += 32) {
            float4 a = ls[threadIdx.x + j], b = lq[threadIdx.x + j];
            s.x += a.x; s.y += a.y; s.z += a.z; s.w += a.w;
            q.x += b.x; q.y += b.y; q.z += b.z; q.w += b.w;
        }
        int f = threadIdx.x * 4;
        atomicAdd(&bnsum[f + 0], s.x); atomicAdd(&bnsum[f + 1], s.y);
        atomicAdd(&bnsum[f + 2], s.z); atomicAdd(&bnsum[f + 3], s.w);
        atomicAdd(&bnsq[f + 0], q.x);  atomicAdd(&bnsq[f + 1], q.y);
        atomicAdd(&bnsq[f + 2], q.z);  atomicAdd(&bnsq[f + 3], q.w);
    }
}

__global__ __launch_bounds__(128) void bnfinal_k(const float* bnsum, const float* bnsq,
                                                 const float* __restrict__ gamma,
                                                 const float* __restrict__ beta,
                                                 float* scale, float* shift, int N) {
    int c = threadIdx.x;
    float mu = bnsum[c] / (float)N;
    float var = bnsq[c] / (float)N - mu * mu;
    var = var > 0.f ? var : 0.f;
    float sc = gamma[c] * rsqrtf(var + BN_EPS);
    scale[c] = sc;
    shift[c] = beta[c] - mu * sc;
}

// ---------------- GEMM2: H2 = relu(BN(X1)) @ W2 ----------------
__global__ __launch_bounds__(256) void gemm2_k(const float* __restrict__ X1,
                                               const float* __restrict__ W2,
                                               const float* __restrict__ scale,
                                               const float* __restrict__ shift,
                                               float* __restrict__ H2, int N) {
    __shared__ float Xs[BK][BM];
    __shared__ float Ws[BK][128];
    int tid = threadIdx.x;
    int row0 = blockIdx.x * BM;
    int tx = tid & 31, ty = tid >> 5;
    float acc[8][4] = {};
    for (int k0 = 0; k0 < 128; k0 += BK) {
        {
            int kk = tid & 31, rb = tid >> 5;
            float sc = scale[k0 + kk], sh = shift[k0 + kk];
            for (int j = 0; j < 8; ++j) {
                int r = rb + 8 * j, row = row0 + r;
                float v = (row < N) ? X1[(long long)row * 128 + k0 + kk] : 0.f;
                v = v * sc + sh;
                Xs[kk][r] = v > 0.f ? v : 0.f;
            }
        }
        {
            int c = tid & 127, kb = tid >> 7;
            for (int j = 0; j < 16; ++j) {
                int kk = kb + 2 * j;
                Ws[kk][c] = (c < D_OUT) ? W2[(k0 + kk) * D_OUT + c] : 0.f;
            }
        }
        __syncthreads();
        for (int kk = 0; kk < BK; ++kk) {
            float4 w = *(const float4*)&Ws[kk][tx * 4];
            float x[8];
            *(float4*)&x[0] = *(const float4*)&Xs[kk][ty * 8];
            *(float4*)&x[4] = *(const float4*)&Xs[kk][ty * 8 + 4];
#pragma unroll
            for (int r = 0; r < 8; ++r) {
                acc[r][0] += x[r] * w.x; acc[r][1] += x[r] * w.y;
                acc[r][2] += x[r] * w.z; acc[r][3] += x[r] * w.w;
            }
        }
        __syncthreads();
    }
    int c = tx * 4;
    if (c < D_OUT) {
        for (int r = 0; r < 8; ++r) {
            int row = row0 + ty * 8 + r;
            if (row < N) *(float4*)&H2[(long long)row * D_OUT + c] = *(float4*)&acc[r][0];
        }
    }
}

// ---------------- agg2 + bias + segment_max pool (batch sorted) ----------------
// 32-lane groups; lanes 0..24 hold float4 (100 feats); 8 chains per block.
__global__ __launch_bounds__(256) void agg2pool_k(const float* __restrict__ H2,
                                                  const int* __restrict__ off,
                                                  const int* __restrict__ csr,
                                                  const float* __restrict__ dinv,
                                                  const int* __restrict__ batch,
                                                  const float* __restrict__ b2,
                                                  unsigned* __restrict__ pool,
                                                  int N, int chunk) {
    int grp = blockIdx.x * 8 + (threadIdx.x >> 5);
    int lane = threadIdx.x & 31;
    if (lane >= 25) return;
    int n0 = grp * chunk;
    int n1 = n0 + chunk; if (n1 > N) n1 = N;
    if (n0 >= n1) return;
    const float4* H4 = (const float4*)H2;   // 25 float4 per row
    float4 bf = ((const float4*)b2)[lane];
    const float ninf = -__builtin_inff();
    float mx = ninf, my = ninf, mz = ninf, mw = ninf;
    int gcur = batch[n0];
    int is = off[n0];
    for (int n = n0; n < n1; ++n) {
        int ie = off[n + 1];
        int gb = batch[n];
        if (gb != gcur) {
            long long pb = (long long)gcur * D_OUT + lane * 4;
            atomicMax(&pool[pb + 0], fmap(mx)); atomicMax(&pool[pb + 1], fmap(my));
            atomicMax(&pool[pb + 2], fmap(mz)); atomicMax(&pool[pb + 3], fmap(mw));
            gcur = gb;
            mx = ninf; my = ninf; mz = ninf; mw = ninf;
        }
        float dn = dinv[n];
        float w = dn * dn;
        float4 h = H4[(long long)n * 25 + lane];
        float ax = w * h.x, ay = w * h.y, az = w * h.z, aw = w * h.w;
        for (int i = is; i < ie; ++i) {
            int s = csr[i];
            float ws = dinv[s] * dn;
            float4 hs = H4[(long long)s * 25 + lane];
            ax += ws * hs.x; ay += ws * hs.y; az += ws * hs.z; aw += ws * hs.w;
        }
        is = ie;
        ax += bf.x; ay += bf.y; az += bf.z; aw += bf.w;
        mx = mx > ax ? mx : ax; my = my > ay ? my : ay;
        mz = mz > az ? mz : az; mw = mw > aw ? mw : aw;
    }
    long long pb = (long long)gcur * D_OUT + lane * 4;
    atomicMax(&pool[pb + 0], fmap(mx)); atomicMax(&pool[pb + 1], fmap(my));
    atomicMax(&pool[pb + 2], fmap(mz)); atomicMax(&pool[pb + 3], fmap(mw));
}

__global__ __launch_bounds__(256) void pool_final_k(const unsigned* __restrict__ pool,
                                                    float* __restrict__ out, int P) {
    int i = blockIdx.x * 256 + threadIdx.x;
    if (i < P) out[i] = funmap(pool[i]);
}

// ---------------- launch ----------------
extern "C" void kernel_launch(void* const* d_in, const int* in_sizes, int n_in,
                              void* d_out, int out_size, void* d_ws, size_t ws_size,
                              hipStream_t stream) {
    const float* X     = (const float*)d_in[0];
    const int*   eidx  = (const int*)d_in[1];
    const int*   batch = (const int*)d_in[2];
    const float* W1    = (const float*)d_in[4];
    // d_in[5] = b1: cancels inside batch_norm
    const float* gamma = (const float*)d_in[6];
    const float* beta  = (const float*)d_in[7];
    const float* W2    = (const float*)d_in[8];
    const float* b2    = (const float*)d_in[9];

    const int N = in_sizes[0] / D_HID;     // 200000
    const int E = in_sizes[1] / 2;         // 600000
    const int P = out_size;                // num_graphs * 100
    const int* src = eidx;
    const int* dst = eidx + E;

    // workspace layout
    char* p = (char*)d_ws;
    auto alloc = [&](size_t bytes) { char* q = p; p += (bytes + 255) & ~(size_t)255; return q; };
    int*      deg    = (int*)alloc((size_t)N * 4);
    int*      cursor = (int*)alloc((size_t)N * 4);
    int*      off    = (int*)alloc((size_t)(N + 1) * 4);
    int*      btot   = (int*)alloc(256 * 4);
    int*      csr    = (int*)alloc((size_t)E * 4);
    float*    dinv   = (float*)alloc((size_t)N * 4);
    float*    bnsum  = (float*)alloc(128 * 4);
    float*    bnsq   = (float*)alloc(128 * 4);
    float*    scale  = (float*)alloc(128 * 4);
    float*    shift  = (float*)alloc(128 * 4);
    unsigned* pool   = (unsigned*)alloc((size_t)P * 4);
    float*    A      = (float*)alloc((size_t)N * 128 * 4);  // H (then H2, stride 100)
    float*    B      = (float*)alloc((size_t)N * 128 * 4);  // X1

    const int nb1 = (N + SCAN_EPB - 1) / SCAN_EPB;          // 196 <= 256
    const int initN = (N > P ? N : P);

    init_k<<<(initN + 255) / 256, 256, 0, stream>>>(deg, cursor, pool, bnsum, bnsq, N, P);
    deg_k<<<(E + 255) / 256, 256, 0, stream>>>(dst, deg, E);
    scan1_k<<<nb1, 256, 0, stream>>>(deg, off, btot, N);
    scan2_k<<<1, 256, 0, stream>>>(btot, nb1, off, N, E);
    scan3_dinv_k<<<(N + 255) / 256, 256, 0, stream>>>(off, btot, deg, dinv, N);
    fill_k<<<(E + 255) / 256, 256, 0, stream>>>(src, dst, off, cursor, csr, E);

    gemm1_k<<<(N + BM - 1) / BM, 256, 0, stream>>>(X, W1, A, N);

    const int nblk_agg = 2048;
    const int ngrp = nblk_agg * 8;
    const int chunk = (N + ngrp - 1) / ngrp;   // 13
    agg1_k<<<nblk_agg, 256, 0, stream>>>(A, off, csr, dinv, B, bnsum, bnsq, N, chunk);
    bnfinal_k<<<1, 128, 0, stream>>>(bnsum, bnsq, gamma, beta, scale, shift, N);

    gemm2_k<<<(N + BM - 1) / BM, 256, 0, stream>>>(B, W2, scale, shift, A, N);

    agg2pool_k<<<nblk_agg, 256, 0, stream>>>(A, off, csr, dinv, batch, b2, pool, N, chunk);
    pool_final_k<<<(P + 255) / 256, 256, 0, stream>>>(pool, (float*)d_out, P);
}

// Round 4
// 540.093 us; speedup vs baseline: 1.2422x; 1.2422x over previous
//
#include <hip/hip_runtime.h>
#include <hip/hip_bf16.h>

#define D_HID 128
#define D_OUT 100
#define BN_EPS 1e-5f

// ---------------- helpers ----------------
__device__ __forceinline__ unsigned fmap(float f) {
    unsigned u = __float_as_uint(f);
    return (u & 0x80000000u) ? ~u : (u | 0x80000000u);
}
__device__ __forceinline__ float funmap(unsigned u) {
    return __uint_as_float((u & 0x80000000u) ? (u ^ 0x80000000u) : ~u);
}
#define NEG_INF_MAPPED 0x007FFFFFu  // fmap(-inf)

// ---------------- init ----------------
__global__ __launch_bounds__(256) void init_k(int* deg, int* cursor, unsigned* pool,
                                              float* bnsum, float* bnsq, int N, int P) {
    int i = blockIdx.x * 256 + threadIdx.x;
    if (i < N) { deg[i] = 0; cursor[i] = 0; }
    if (i < P) pool[i] = NEG_INF_MAPPED;
    if (i < 128) { bnsum[i] = 0.f; bnsq[i] = 0.f; }
}

__global__ __launch_bounds__(256) void deg_k(const int* __restrict__ dst, int* deg, int E) {
    int e = blockIdx.x * 256 + threadIdx.x;
    if (e < E) atomicAdd(&deg[dst[e]], 1);
}

// ---------------- exclusive scan over deg -> off (2-level) ----------------
#define SCAN_EPB 1024
__global__ __launch_bounds__(256) void scan1_k(const int* __restrict__ deg, int* __restrict__ off,
                                               int* __restrict__ btot, int N) {
    __shared__ int ts[256];
    int base = blockIdx.x * SCAN_EPB + threadIdx.x * 4;
    int v[4];
    int s = 0;
#pragma unroll
    for (int j = 0; j < 4; ++j) { int idx = base + j; v[j] = (idx < N) ? deg[idx] : 0; s += v[j]; }
    ts[threadIdx.x] = s;
    __syncthreads();
    for (int d = 1; d < 256; d <<= 1) {
        int t = (threadIdx.x >= d) ? ts[threadIdx.x - d] : 0;
        __syncthreads();
        ts[threadIdx.x] += t;
        __syncthreads();
    }
    int excl = ts[threadIdx.x] - s;
#pragma unroll
    for (int j = 0; j < 4; ++j) { int idx = base + j; if (idx < N) off[idx] = excl; excl += v[j]; }
    if (threadIdx.x == 255) btot[blockIdx.x] = ts[255];
}

__global__ __launch_bounds__(256) void scan2_k(int* btot, int nb, int* off, int N, int E) {
    __shared__ int ts[256];
    int v = (threadIdx.x < nb) ? btot[threadIdx.x] : 0;
    ts[threadIdx.x] = v;
    __syncthreads();
    for (int d = 1; d < 256; d <<= 1) {
        int t = (threadIdx.x >= d) ? ts[threadIdx.x - d] : 0;
        __syncthreads();
        ts[threadIdx.x] += t;
        __syncthreads();
    }
    if (threadIdx.x < nb) btot[threadIdx.x] = ts[threadIdx.x] - v;  // exclusive
    if (threadIdx.x == 0) off[N] = E;
}

__global__ __launch_bounds__(256) void scan3_dinv_k(int* off, const int* __restrict__ btot,
                                                    const int* __restrict__ deg,
                                                    float* __restrict__ dinv, int N) {
    int i = blockIdx.x * 256 + threadIdx.x;
    if (i < N) {
        off[i] += btot[i / SCAN_EPB];
        dinv[i] = rsqrtf((float)(1 + deg[i]));  // +1 self-loop
    }
}

// fill CSR as (src, weight) pairs; weight = dinv[src]*dinv[dst]
__global__ __launch_bounds__(256) void fill_k(const int* __restrict__ src, const int* __restrict__ dst,
                                              const int* __restrict__ off, int* cursor,
                                              const float* __restrict__ dinv,
                                              int2* __restrict__ ep, int E) {
    int e = blockIdx.x * 256 + threadIdx.x;
    if (e < E) {
        int d = dst[e];
        int s = src[e];
        int p = atomicAdd(&cursor[d], 1);
        int2 v;
        v.x = s;
        v.y = __float_as_int(dinv[s] * dinv[d]);
        ep[off[d] + p] = v;
    }
}

// ---------------- GEMM1: H = X @ W1  (f32, 64x128 tile) ----------------
#define BM 64
#define BK 32
__global__ __launch_bounds__(256) void gemm1_k(const float* __restrict__ X,
                                               const float* __restrict__ W,
                                               float* __restrict__ H, int N) {
    __shared__ float Xs[BK][BM];
    __shared__ float Ws[BK][128];
    int tid = threadIdx.x;
    int row0 = blockIdx.x * BM;
    int tx = tid & 31, ty = tid >> 5;
    float acc[8][4] = {};
    for (int k0 = 0; k0 < 128; k0 += BK) {
        {
            int kk = tid & 31, rb = tid >> 5;
            for (int j = 0; j < 8; ++j) {
                int r = rb + 8 * j, row = row0 + r;
                Xs[kk][r] = (row < N) ? X[(long long)row * 128 + k0 + kk] : 0.f;
            }
        }
        {
            int c = tid & 127, kb = tid >> 7;
            for (int j = 0; j < 16; ++j) {
                int kk = kb + 2 * j;
                Ws[kk][c] = W[(k0 + kk) * 128 + c];
            }
        }
        __syncthreads();
        for (int kk = 0; kk < BK; ++kk) {
            float4 w = *(const float4*)&Ws[kk][tx * 4];
            float x[8];
            *(float4*)&x[0] = *(const float4*)&Xs[kk][ty * 8];
            *(float4*)&x[4] = *(const float4*)&Xs[kk][ty * 8 + 4];
#pragma unroll
            for (int r = 0; r < 8; ++r) {
                acc[r][0] += x[r] * w.x; acc[r][1] += x[r] * w.y;
                acc[r][2] += x[r] * w.z; acc[r][3] += x[r] * w.w;
            }
        }
        __syncthreads();
    }
    for (int r = 0; r < 8; ++r) {
        int row = row0 + ty * 8 + r;
        if (row < N) *(float4*)&H[(long long)row * 128 + tx * 4] = *(float4*)&acc[r][0];
    }
}

// ---------------- agg1: X1 = Dinv(A+I)Dinv H, fused BN stats ----------------
// One 64-lane wave per group (float2/lane = 128 feats). Flat edge stream,
// 4-batched gathers for MLP; inline node flush; next-self-row prefetch.
#define A1_FLUSH_ADV()                                                  \
    do {                                                                \
        X1v[(long long)n * 64 + lane] = acc;                            \
        bs.x += acc.x; bs.y += acc.y;                                   \
        bq.x += acc.x * acc.x; bq.y += acc.y * acc.y;                   \
        ++n;                                                            \
        nend = off[n + 1];                                              \
        float dn_ = dinv[n];                                            \
        hcur = hnext;                                                   \
        int np_ = (n + 1 < N) ? (n + 1) : (N - 1);                      \
        hnext = Hv[(long long)np_ * 64 + lane];                         \
        acc.x = dn_ * dn_ * hcur.x; acc.y = dn_ * dn_ * hcur.y;         \
    } while (0)

__global__ __launch_bounds__(256) void agg1_k(const float* __restrict__ H,
                                              const int* __restrict__ off,
                                              const int2* __restrict__ ep,
                                              const float* __restrict__ dinv,
                                              float* __restrict__ X1,
                                              float* bnsum, float* bnsq,
                                              int N, int chunk) {
    int grp = blockIdx.x * 4 + (threadIdx.x >> 6);
    int lane = threadIdx.x & 63;
    int n0 = grp * chunk;
    int n1 = n0 + chunk; if (n1 > N) n1 = N;
    float2 bs; bs.x = 0.f; bs.y = 0.f;
    float2 bq; bq.x = 0.f; bq.y = 0.f;
    const float2* Hv = (const float2*)H;
    float2* X1v = (float2*)X1;
    if (n0 < n1) {
        int n = n0;
        int i = off[n0];
        int eend = off[n1];
        int nend = off[n0 + 1];
        float dn0 = dinv[n0];
        float2 hcur = Hv[(long long)n0 * 64 + lane];
        int np0 = (n0 + 1 < N) ? (n0 + 1) : (N - 1);
        float2 hnext = Hv[(long long)np0 * 64 + lane];
        float2 acc; acc.x = dn0 * dn0 * hcur.x; acc.y = dn0 * dn0 * hcur.y;
        while (i + 4 <= eend) {
            int2 e0 = ep[i], e1 = ep[i + 1], e2 = ep[i + 2], e3 = ep[i + 3];
            float2 g0 = Hv[(long long)e0.x * 64 + lane];
            float2 g1 = Hv[(long long)e1.x * 64 + lane];
            float2 g2 = Hv[(long long)e2.x * 64 + lane];
            float2 g3 = Hv[(long long)e3.x * 64 + lane];
            while (i >= nend) A1_FLUSH_ADV();
            float w0 = __int_as_float(e0.y); acc.x += w0 * g0.x; acc.y += w0 * g0.y;
            while (i + 1 >= nend) A1_FLUSH_ADV();
            float w1 = __int_as_float(e1.y); acc.x += w1 * g1.x; acc.y += w1 * g1.y;
            while (i + 2 >= nend) A1_FLUSH_ADV();
            float w2 = __int_as_float(e2.y); acc.x += w2 * g2.x; acc.y += w2 * g2.y;
            while (i + 3 >= nend) A1_FLUSH_ADV();
            float w3 = __int_as_float(e3.y); acc.x += w3 * g3.x; acc.y += w3 * g3.y;
            i += 4;
        }
        while (i < eend) {
            int2 e0 = ep[i];
            float2 g0 = Hv[(long long)e0.x * 64 + lane];
            while (i >= nend) A1_FLUSH_ADV();
            float w0 = __int_as_float(e0.y); acc.x += w0 * g0.x; acc.y += w0 * g0.y;
            ++i;
        }
        for (;;) {  // trailing flushes (current node + any zero-edge tail)
            X1v[(long long)n * 64 + lane] = acc;
            bs.x += acc.x; bs.y += acc.y;
            bq.x += acc.x * acc.x; bq.y += acc.y * acc.y;
            ++n;
            if (n >= n1) break;
            float dn_ = dinv[n];
            hcur = hnext;
            int np_ = (n + 1 < N) ? (n + 1) : (N - 1);
            hnext = Hv[(long long)np_ * 64 + lane];
            acc.x = dn_ * dn_ * hcur.x; acc.y = dn_ * dn_ * hcur.y;
        }
    }
    __shared__ float2 ls[256], lq[256];
    ls[threadIdx.x] = bs; lq[threadIdx.x] = bq;
    __syncthreads();
    if (threadIdx.x < 64) {
        float2 s = ls[threadIdx.x], q = lq[threadIdx.x];
#pragma unroll
        for (int j = 64; j < 256; j += 64) {
            float2 a = ls[threadIdx.x + j], b = lq[threadIdx.x + j];
            s.x += a.x; s.y += a.y; q.x += b.x; q.y += b.y;
        }
        atomicAdd(&bnsum[threadIdx.x * 2 + 0], s.x);
        atomicAdd(&bnsum[threadIdx.x * 2 + 1], s.y);
        atomicAdd(&bnsq[threadIdx.x * 2 + 0], q.x);
        atomicAdd(&bnsq[threadIdx.x * 2 + 1], q.y);
    }
}

__global__ __launch_bounds__(128) void bnfinal_k(const float* bnsum, const float* bnsq,
                                                 const float* __restrict__ gamma,
                                                 const float* __restrict__ beta,
                                                 float* scale, float* shift, int N) {
    int c = threadIdx.x;
    float mu = bnsum[c] / (float)N;
    float var = bnsq[c] / (float)N - mu * mu;
    var = var > 0.f ? var : 0.f;
    float sc = gamma[c] * rsqrtf(var + BN_EPS);
    scale[c] = sc;
    shift[c] = beta[c] - mu * sc;
}

// ---------------- GEMM2: H2 = relu(BN(X1)) @ W2 ----------------
__global__ __launch_bounds__(256) void gemm2_k(const float* __restrict__ X1,
                                               const float* __restrict__ W2,
                                               const float* __restrict__ scale,
                                               const float* __restrict__ shift,
                                               float* __restrict__ H2, int N) {
    __shared__ float Xs[BK][BM];
    __shared__ float Ws[BK][128];
    int tid = threadIdx.x;
    int row0 = blockIdx.x * BM;
    int tx = tid & 31, ty = tid >> 5;
    float acc[8][4] = {};
    for (int k0 = 0; k0 < 128; k0 += BK) {
        {
            int kk = tid & 31, rb = tid >> 5;
            float sc = scale[k0 + kk], sh = shift[k0 + kk];
            for (int j = 0; j < 8; ++j) {
                int r = rb + 8 * j, row = row0 + r;
                float v = (row < N) ? X1[(long long)row * 128 + k0 + kk] : 0.f;
                v = v * sc + sh;
                Xs[kk][r] = v > 0.f ? v : 0.f;
            }
        }
        {
            int c = tid & 127, kb = tid >> 7;
            for (int j = 0; j < 16; ++j) {
                int kk = kb + 2 * j;
                Ws[kk][c] = (c < D_OUT) ? W2[(k0 + kk) * D_OUT + c] : 0.f;
            }
        }
        __syncthreads();
        for (int kk = 0; kk < BK; ++kk) {
            float4 w = *(const float4*)&Ws[kk][tx * 4];
            float x[8];
            *(float4*)&x[0] = *(const float4*)&Xs[kk][ty * 8];
            *(float4*)&x[4] = *(const float4*)&Xs[kk][ty * 8 + 4];
#pragma unroll
            for (int r = 0; r < 8; ++r) {
                acc[r][0] += x[r] * w.x; acc[r][1] += x[r] * w.y;
                acc[r][2] += x[r] * w.z; acc[r][3] += x[r] * w.w;
            }
        }
        __syncthreads();
    }
    int c = tx * 4;
    if (c < D_OUT) {
        for (int r = 0; r < 8; ++r) {
            int row = row0 + ty * 8 + r;
            if (row < N) *(float4*)&H2[(long long)row * D_OUT + c] = *(float4*)&acc[r][0];
        }
    }
}

// ---------------- agg2 + bias + segment_max pool (batch sorted) ----------------
// One 64-lane wave per group; lanes 0..49 hold float2 (100 feats).
#define NINF (-__builtin_inff())
#define A2_FLUSH_ADV()                                                  \
    do {                                                                \
        float vx_ = acc.x + bf.x, vy_ = acc.y + bf.y;                   \
        int gb_ = batch[n];                                             \
        if (gb_ != gcur) {                                              \
            long long pb_ = (long long)gcur * D_OUT + lane * 2;         \
            atomicMax(&pool[pb_], fmap(mx));                            \
            atomicMax(&pool[pb_ + 1], fmap(my));                        \
            gcur = gb_; mx = NINF; my = NINF;                           \
        }                                                               \
        mx = mx > vx_ ? mx : vx_; my = my > vy_ ? my : vy_;             \
        ++n;                                                            \
        nend = off[n + 1];                                              \
        float dn_ = dinv[n];                                            \
        hcur = hnext;                                                   \
        int np_ = (n + 1 < N) ? (n + 1) : (N - 1);                      \
        hnext = Hv[(long long)np_ * 50 + lane];                         \
        acc.x = dn_ * dn_ * hcur.x; acc.y = dn_ * dn_ * hcur.y;         \
    } while (0)

__global__ __launch_bounds__(256) void agg2pool_k(const float* __restrict__ H2,
                                                  const int* __restrict__ off,
                                                  const int2* __restrict__ ep,
                                                  const float* __restrict__ dinv,
                                                  const int* __restrict__ batch,
                                                  const float* __restrict__ b2,
                                                  unsigned* __restrict__ pool,
                                                  int N, int chunk) {
    int grp = blockIdx.x * 4 + (threadIdx.x >> 6);
    int lane = threadIdx.x & 63;
    if (lane >= 50) return;
    int n0 = grp * chunk;
    int n1 = n0 + chunk; if (n1 > N) n1 = N;
    if (n0 >= n1) return;
    const float2* Hv = (const float2*)H2;  // 50 float2 per row
    float2 bf = ((const float2*)b2)[lane];
    float mx = NINF, my = NINF;
    int gcur = batch[n0];
    int n = n0;
    int i = off[n0];
    int eend = off[n1];
    int nend = off[n0 + 1];
    float dn0 = dinv[n0];
    float2 hcur = Hv[(long long)n0 * 50 + lane];
    int np0 = (n0 + 1 < N) ? (n0 + 1) : (N - 1);
    float2 hnext = Hv[(long long)np0 * 50 + lane];
    float2 acc; acc.x = dn0 * dn0 * hcur.x; acc.y = dn0 * dn0 * hcur.y;
    while (i + 4 <= eend) {
        int2 e0 = ep[i], e1 = ep[i + 1], e2 = ep[i + 2], e3 = ep[i + 3];
        float2 g0 = Hv[(long long)e0.x * 50 + lane];
        float2 g1 = Hv[(long long)e1.x * 50 + lane];
        float2 g2 = Hv[(long long)e2.x * 50 + lane];
        float2 g3 = Hv[(long long)e3.x * 50 + lane];
        while (i >= nend) A2_FLUSH_ADV();
        float w0 = __int_as_float(e0.y); acc.x += w0 * g0.x; acc.y += w0 * g0.y;
        while (i + 1 >= nend) A2_FLUSH_ADV();
        float w1 = __int_as_float(e1.y); acc.x += w1 * g1.x; acc.y += w1 * g1.y;
        while (i + 2 >= nend) A2_FLUSH_ADV();
        float w2 = __int_as_float(e2.y); acc.x += w2 * g2.x; acc.y += w2 * g2.y;
        while (i + 3 >= nend) A2_FLUSH_ADV();
        float w3 = __int_as_float(e3.y); acc.x += w3 * g3.x; acc.y += w3 * g3.y;
        i += 4;
    }
    while (i < eend) {
        int2 e0 = ep[i];
        float2 g0 = Hv[(long long)e0.x * 50 + lane];
        while (i >= nend) A2_FLUSH_ADV();
        float w0 = __int_as_float(e0.y); acc.x += w0 * g0.x; acc.y += w0 * g0.y;
        ++i;
    }
    for (;;) {  // trailing flushes
        float vx_ = acc.x + bf.x, vy_ = acc.y + bf.y;
        int gb_ = batch[n];
        if (gb_ != gcur) {
            long long pb_ = (long long)gcur * D_OUT + lane * 2;
            atomicMax(&pool[pb_], fmap(mx));
            atomicMax(&pool[pb_ + 1], fmap(my));
            gcur = gb_; mx = NINF; my = NINF;
        }
        mx = mx > vx_ ? mx : vx_; my = my > vy_ ? my : vy_;
        ++n;
        if (n >= n1) break;
        float dn_ = dinv[n];
        hcur = hnext;
        int np_ = (n + 1 < N) ? (n + 1) : (N - 1);
        hnext = Hv[(long long)np_ * 50 + lane];
        acc.x = dn_ * dn_ * hcur.x; acc.y = dn_ * dn_ * hcur.y;
    }
    long long pb = (long long)gcur * D_OUT + lane * 2;
    atomicMax(&pool[pb], fmap(mx));
    atomicMax(&pool[pb + 1], fmap(my));
}

__global__ __launch_bounds__(256) void pool_final_k(const unsigned* __restrict__ pool,
                                                    float* __restrict__ out, int P) {
    int i = blockIdx.x * 256 + threadIdx.x;
    if (i < P) out[i] = funmap(pool[i]);
}

// ---------------- launch ----------------
extern "C" void kernel_launch(void* const* d_in, const int* in_sizes, int n_in,
                              void* d_out, int out_size, void* d_ws, size_t ws_size,
                              hipStream_t stream) {
    const float* X     = (const float*)d_in[0];
    const int*   eidx  = (const int*)d_in[1];
    const int*   batch = (const int*)d_in[2];
    const float* W1    = (const float*)d_in[4];
    // d_in[5] = b1: cancels inside batch_norm
    const float* gamma = (const float*)d_in[6];
    const float* beta  = (const float*)d_in[7];
    const float* W2    = (const float*)d_in[8];
    const float* b2    = (const float*)d_in[9];

    const int N = in_sizes[0] / D_HID;     // 200000
    const int E = in_sizes[1] / 2;         // 600000
    const int P = out_size;                // num_graphs * 100
    const int* src = eidx;
    const int* dst = eidx + E;

    // workspace layout
    char* p = (char*)d_ws;
    auto alloc = [&](size_t bytes) { char* q = p; p += (bytes + 255) & ~(size_t)255; return q; };
    int*      deg    = (int*)alloc((size_t)N * 4);
    int*      cursor = (int*)alloc((size_t)N * 4);
    int*      off    = (int*)alloc((size_t)(N + 1) * 4);
    int*      btot   = (int*)alloc(256 * 4);
    int2*     ep     = (int2*)alloc((size_t)E * 8);
    float*    dinv   = (float*)alloc((size_t)N * 4);
    float*    bnsum  = (float*)alloc(128 * 4);
    float*    bnsq   = (float*)alloc(128 * 4);
    float*    scale  = (float*)alloc(128 * 4);
    float*    shift  = (float*)alloc(128 * 4);
    unsigned* pool   = (unsigned*)alloc((size_t)P * 4);
    float*    A      = (float*)alloc((size_t)N * 128 * 4);  // H (then H2, stride 100)
    float*    B      = (float*)alloc((size_t)N * 128 * 4);  // X1

    const int nb1 = (N + SCAN_EPB - 1) / SCAN_EPB;          // 196 <= 256
    const int initN = (N > P ? N : P);

    init_k<<<(initN + 255) / 256, 256, 0, stream>>>(deg, cursor, pool, bnsum, bnsq, N, P);
    deg_k<<<(E + 255) / 256, 256, 0, stream>>>(dst, deg, E);
    scan1_k<<<nb1, 256, 0, stream>>>(deg, off, btot, N);
    scan2_k<<<1, 256, 0, stream>>>(btot, nb1, off, N, E);
    scan3_dinv_k<<<(N + 255) / 256, 256, 0, stream>>>(off, btot, deg, dinv, N);
    fill_k<<<(E + 255) / 256, 256, 0, stream>>>(src, dst, off, cursor, dinv, ep, E);

    gemm1_k<<<(N + BM - 1) / BM, 256, 0, stream>>>(X, W1, A, N);

    const int nblk_agg = 2048;
    const int ngrp = nblk_agg * 4;                 // one 64-lane wave per group
    const int chunk = (N + ngrp - 1) / ngrp;       // 25
    agg1_k<<<nblk_agg, 256, 0, stream>>>(A, off, ep, dinv, B, bnsum, bnsq, N, chunk);
    bnfinal_k<<<1, 128, 0, stream>>>(bnsum, bnsq, gamma, beta, scale, shift, N);

    gemm2_k<<<(N + BM - 1) / BM, 256, 0, stream>>>(B, W2, scale, shift, A, N);

    agg2pool_k<<<nblk_agg, 256, 0, stream>>>(A, off, ep, dinv, batch, b2, pool, N, chunk);
    pool_final_k<<<(P + 255) / 256, 256, 0, stream>>>(pool, (float*)d_out, P);
}

// Round 5
// 465.019 us; speedup vs baseline: 1.4427x; 1.1614x over previous
//
#include <hip/hip_runtime.h>
#include <hip/hip_bf16.h>

#define D_HID 128
#define D_OUT 100
#define BN_EPS 1e-5f

// ---------------- helpers ----------------
__device__ __forceinline__ unsigned fmap(float f) {
    unsigned u = __float_as_uint(f);
    return (u & 0x80000000u) ? ~u : (u | 0x80000000u);
}
__device__ __forceinline__ float funmap(unsigned u) {
    return __uint_as_float((u & 0x80000000u) ? (u ^ 0x80000000u) : ~u);
}
#define NEG_INF_MAPPED 0x007FFFFFu  // fmap(-inf)

__device__ __forceinline__ unsigned short f2bf(float f) {  // RNE f32->bf16
    unsigned u = __float_as_uint(f);
    return (unsigned short)((u + 0x7fffu + ((u >> 16) & 1u)) >> 16);
}
__device__ __forceinline__ unsigned packbf2(float x, float y) {
    return (unsigned)f2bf(x) | ((unsigned)f2bf(y) << 16);
}
__device__ __forceinline__ float2 unpackbf2(unsigned v) {
    float2 r;
    r.x = __uint_as_float(v << 16);
    r.y = __uint_as_float(v & 0xffff0000u);
    return r;
}

// ---------------- init ----------------
__global__ __launch_bounds__(256) void init_k(int* deg, int* cursor, unsigned* pool,
                                              float* bnsum, float* bnsq, int N, int P) {
    int i = blockIdx.x * 256 + threadIdx.x;
    if (i < N) { deg[i] = 0; cursor[i] = 0; }
    if (i < P) pool[i] = NEG_INF_MAPPED;
    if (i < 128) { bnsum[i] = 0.f; bnsq[i] = 0.f; }
}

__global__ __launch_bounds__(256) void deg_k(const int* __restrict__ dst, int* deg, int E) {
    int e = blockIdx.x * 256 + threadIdx.x;
    if (e < E) atomicAdd(&deg[dst[e]], 1);
}

// ---------------- exclusive scan over deg -> off (2-level) ----------------
#define SCAN_EPB 1024
__global__ __launch_bounds__(256) void scan1_k(const int* __restrict__ deg, int* __restrict__ off,
                                               int* __restrict__ btot, int N) {
    __shared__ int ts[256];
    int base = blockIdx.x * SCAN_EPB + threadIdx.x * 4;
    int v[4];
    int s = 0;
#pragma unroll
    for (int j = 0; j < 4; ++j) { int idx = base + j; v[j] = (idx < N) ? deg[idx] : 0; s += v[j]; }
    ts[threadIdx.x] = s;
    __syncthreads();
    for (int d = 1; d < 256; d <<= 1) {
        int t = (threadIdx.x >= d) ? ts[threadIdx.x - d] : 0;
        __syncthreads();
        ts[threadIdx.x] += t;
        __syncthreads();
    }
    int excl = ts[threadIdx.x] - s;
#pragma unroll
    for (int j = 0; j < 4; ++j) { int idx = base + j; if (idx < N) off[idx] = excl; excl += v[j]; }
    if (threadIdx.x == 255) btot[blockIdx.x] = ts[255];
}

__global__ __launch_bounds__(256) void scan2_k(int* btot, int nb, int* off, int N, int E) {
    __shared__ int ts[256];
    int v = (threadIdx.x < nb) ? btot[threadIdx.x] : 0;
    ts[threadIdx.x] = v;
    __syncthreads();
    for (int d = 1; d < 256; d <<= 1) {
        int t = (threadIdx.x >= d) ? ts[threadIdx.x - d] : 0;
        __syncthreads();
        ts[threadIdx.x] += t;
        __syncthreads();
    }
    if (threadIdx.x < nb) btot[threadIdx.x] = ts[threadIdx.x] - v;  // exclusive
    if (threadIdx.x == 0) off[N] = E;
}

__global__ __launch_bounds__(256) void scan3_dinv_k(int* off, const int* __restrict__ btot,
                                                    const int* __restrict__ deg,
                                                    float* __restrict__ dinv, int N) {
    int i = blockIdx.x * 256 + threadIdx.x;
    if (i < N) {
        off[i] += btot[i / SCAN_EPB];
        dinv[i] = rsqrtf((float)(1 + deg[i]));  // +1 self-loop
    }
}

__global__ __launch_bounds__(256) void fill_k(const int* __restrict__ src, const int* __restrict__ dst,
                                              const int* __restrict__ off, int* cursor,
                                              int* __restrict__ csr, int E) {
    int e = blockIdx.x * 256 + threadIdx.x;
    if (e < E) {
        int d = dst[e];
        int p = atomicAdd(&cursor[d], 1);
        csr[off[d] + p] = src[e];
    }
}

// ---------------- GEMM1: H' = dinv .* (X @ W1), bf16 out ----------------
#define BM 64
#define BK 32
__global__ __launch_bounds__(256) void gemm1_k(const float* __restrict__ X,
                                               const float* __restrict__ W,
                                               const float* __restrict__ dinv,
                                               unsigned* __restrict__ H, int N) {
    __shared__ float Xs[BK][BM];
    __shared__ float Ws[BK][128];
    int tid = threadIdx.x;
    int row0 = blockIdx.x * BM;
    int tx = tid & 31, ty = tid >> 5;
    float acc[8][4] = {};
    for (int k0 = 0; k0 < 128; k0 += BK) {
        {
            int kk = tid & 31, rb = tid >> 5;
            for (int j = 0; j < 8; ++j) {
                int r = rb + 8 * j, row = row0 + r;
                Xs[kk][r] = (row < N) ? X[(long long)row * 128 + k0 + kk] : 0.f;
            }
        }
        {
            int c = tid & 127, kb = tid >> 7;
            for (int j = 0; j < 16; ++j) {
                int kk = kb + 2 * j;
                Ws[kk][c] = W[(k0 + kk) * 128 + c];
            }
        }
        __syncthreads();
        for (int kk = 0; kk < BK; ++kk) {
            float4 w = *(const float4*)&Ws[kk][tx * 4];
            float x[8];
            *(float4*)&x[0] = *(const float4*)&Xs[kk][ty * 8];
            *(float4*)&x[4] = *(const float4*)&Xs[kk][ty * 8 + 4];
#pragma unroll
            for (int r = 0; r < 8; ++r) {
                acc[r][0] += x[r] * w.x; acc[r][1] += x[r] * w.y;
                acc[r][2] += x[r] * w.z; acc[r][3] += x[r] * w.w;
            }
        }
        __syncthreads();
    }
    for (int r = 0; r < 8; ++r) {
        int row = row0 + ty * 8 + r;
        if (row < N) {
            float dn = dinv[row];
            uint2 o;
            o.x = packbf2(acc[r][0] * dn, acc[r][1] * dn);
            o.y = packbf2(acc[r][2] * dn, acc[r][3] * dn);
            *(uint2*)&H[(long long)row * 64 + tx * 2] = o;
        }
    }
}

// ---------------- agg1: X1 = dinv .* (H' + sum_nbr H'), fused BN stats ----------------
// One 64-lane wave per group; 1 uint (2 bf16 feats) per lane = 256 B/row.
#define A1_FLUSH_ADV()                                                  \
    do {                                                                \
        float ox = dncur * acc.x, oy = dncur * acc.y;                   \
        X1[(long long)n * 64 + lane] = packbf2(ox, oy);                 \
        bs.x += ox; bs.y += oy;                                         \
        bq.x += ox * ox; bq.y += oy * oy;                               \
        ++n;                                                            \
        nend = off[n + 1];                                              \
        dncur = dinv[n];                                                \
        acc = unpackbf2(hnext);                                         \
        int np_ = (n + 1 < N) ? (n + 1) : (N - 1);                      \
        hnext = H[(long long)np_ * 64 + lane];                          \
    } while (0)

__global__ __launch_bounds__(256) void agg1_k(const unsigned* __restrict__ H,
                                              const int* __restrict__ off,
                                              const int* __restrict__ csr,
                                              const float* __restrict__ dinv,
                                              unsigned* __restrict__ X1,
                                              float* bnsum, float* bnsq,
                                              int N, int chunk) {
    int grp = blockIdx.x * 4 + (threadIdx.x >> 6);
    int lane = threadIdx.x & 63;
    int n0 = grp * chunk;
    int n1 = n0 + chunk; if (n1 > N) n1 = N;
    float2 bs; bs.x = 0.f; bs.y = 0.f;
    float2 bq; bq.x = 0.f; bq.y = 0.f;
    if (n0 < n1) {
        int n = n0;
        int i = off[n0];
        int eend = off[n1];
        int nend = off[n0 + 1];
        float dncur = dinv[n0];
        float2 acc = unpackbf2(H[(long long)n0 * 64 + lane]);
        int np0 = (n0 + 1 < N) ? (n0 + 1) : (N - 1);
        unsigned hnext = H[(long long)np0 * 64 + lane];
        while (i + 4 <= eend) {
            int s0 = csr[i], s1 = csr[i + 1], s2 = csr[i + 2], s3 = csr[i + 3];
            unsigned g0 = H[(long long)s0 * 64 + lane];
            unsigned g1 = H[(long long)s1 * 64 + lane];
            unsigned g2 = H[(long long)s2 * 64 + lane];
            unsigned g3 = H[(long long)s3 * 64 + lane];
            while (i >= nend) A1_FLUSH_ADV();
            { float2 f = unpackbf2(g0); acc.x += f.x; acc.y += f.y; }
            while (i + 1 >= nend) A1_FLUSH_ADV();
            { float2 f = unpackbf2(g1); acc.x += f.x; acc.y += f.y; }
            while (i + 2 >= nend) A1_FLUSH_ADV();
            { float2 f = unpackbf2(g2); acc.x += f.x; acc.y += f.y; }
            while (i + 3 >= nend) A1_FLUSH_ADV();
            { float2 f = unpackbf2(g3); acc.x += f.x; acc.y += f.y; }
            i += 4;
        }
        while (i < eend) {
            int s0 = csr[i];
            unsigned g0 = H[(long long)s0 * 64 + lane];
            while (i >= nend) A1_FLUSH_ADV();
            { float2 f = unpackbf2(g0); acc.x += f.x; acc.y += f.y; }
            ++i;
        }
        for (;;) {  // trailing flushes
            float ox = dncur * acc.x, oy = dncur * acc.y;
            X1[(long long)n * 64 + lane] = packbf2(ox, oy);
            bs.x += ox; bs.y += oy;
            bq.x += ox * ox; bq.y += oy * oy;
            ++n;
            if (n >= n1) break;
            dncur = dinv[n];
            acc = unpackbf2(hnext);
            int np_ = (n + 1 < N) ? (n + 1) : (N - 1);
            hnext = H[(long long)np_ * 64 + lane];
        }
    }
    __shared__ float2 ls[256], lq[256];
    ls[threadIdx.x] = bs; lq[threadIdx.x] = bq;
    __syncthreads();
    if (threadIdx.x < 64) {
        float2 s = ls[threadIdx.x], q = lq[threadIdx.x];
#pragma unroll
        for (int j = 64; j < 256; j += 64) {
            float2 a = ls[threadIdx.x + j], b = lq[threadIdx.x + j];
            s.x += a.x; s.y += a.y; q.x += b.x; q.y += b.y;
        }
        atomicAdd(&bnsum[threadIdx.x * 2 + 0], s.x);
        atomicAdd(&bnsum[threadIdx.x * 2 + 1], s.y);
        atomicAdd(&bnsq[threadIdx.x * 2 + 0], q.x);
        atomicAdd(&bnsq[threadIdx.x * 2 + 1], q.y);
    }
}

__global__ __launch_bounds__(128) void bnfinal_k(const float* bnsum, const float* bnsq,
                                                 const float* __restrict__ gamma,
                                                 const float* __restrict__ beta,
                                                 float* scale, float* shift, int N) {
    int c = threadIdx.x;
    float mu = bnsum[c] / (float)N;
    float var = bnsq[c] / (float)N - mu * mu;
    var = var > 0.f ? var : 0.f;
    float sc = gamma[c] * rsqrtf(var + BN_EPS);
    scale[c] = sc;
    shift[c] = beta[c] - mu * sc;
}

// ---------------- GEMM2: H2' = dinv .* (relu(BN(X1)) @ W2), bf16 in/out ----------------
__global__ __launch_bounds__(256) void gemm2_k(const unsigned* __restrict__ X1,
                                               const float* __restrict__ W2,
                                               const float* __restrict__ scale,
                                               const float* __restrict__ shift,
                                               const float* __restrict__ dinv,
                                               unsigned* __restrict__ H2, int N) {
    __shared__ float Xs[BK][BM];
    __shared__ float Ws[BK][128];
    __shared__ float scs[128], shs[128];
    int tid = threadIdx.x;
    if (tid < 128) { scs[tid] = scale[tid]; shs[tid] = shift[tid]; }
    int row0 = blockIdx.x * BM;
    int tx = tid & 31, ty = tid >> 5;
    float acc[8][4] = {};
    __syncthreads();
    for (int k0 = 0; k0 < 128; k0 += BK) {
        {
            int r = tid >> 2, c4 = tid & 3;
            int row = row0 + r;
            uint4 u;
            if (row < N) u = ((const uint4*)X1)[(long long)row * 16 + (k0 >> 3) + c4];
            else { u.x = 0; u.y = 0; u.z = 0; u.w = 0; }
            int kb = c4 * 8;
#pragma unroll
            for (int jj = 0; jj < 4; ++jj) {
                unsigned uu = (&u.x)[jj];
                float2 f = unpackbf2(uu);
                int f0 = k0 + kb + jj * 2;
                float v0 = f.x * scs[f0] + shs[f0];
                float v1 = f.y * scs[f0 + 1] + shs[f0 + 1];
                Xs[kb + jj * 2][r] = v0 > 0.f ? v0 : 0.f;
                Xs[kb + jj * 2 + 1][r] = v1 > 0.f ? v1 : 0.f;
            }
        }
        {
            int c = tid & 127, kb = tid >> 7;
            for (int j = 0; j < 16; ++j) {
                int kk = kb + 2 * j;
                Ws[kk][c] = (c < D_OUT) ? W2[(k0 + kk) * D_OUT + c] : 0.f;
            }
        }
        __syncthreads();
        for (int kk = 0; kk < BK; ++kk) {
            float4 w = *(const float4*)&Ws[kk][tx * 4];
            float x[8];
            *(float4*)&x[0] = *(const float4*)&Xs[kk][ty * 8];
            *(float4*)&x[4] = *(const float4*)&Xs[kk][ty * 8 + 4];
#pragma unroll
            for (int r = 0; r < 8; ++r) {
                acc[r][0] += x[r] * w.x; acc[r][1] += x[r] * w.y;
                acc[r][2] += x[r] * w.z; acc[r][3] += x[r] * w.w;
            }
        }
        __syncthreads();
    }
    int c = tx * 4;
    if (c < D_OUT) {
        for (int r = 0; r < 8; ++r) {
            int row = row0 + ty * 8 + r;
            if (row < N) {
                float dn = dinv[row];
                uint2 o;
                o.x = packbf2(acc[r][0] * dn, acc[r][1] * dn);
                o.y = packbf2(acc[r][2] * dn, acc[r][3] * dn);
                *(uint2*)&H2[(long long)row * 50 + tx * 2] = o;
            }
        }
    }
}

// ---------------- agg2 + bias + segment_max pool (batch sorted) ----------------
// One 64-lane wave per group; lanes 0..49 hold 1 uint (2 feats) = 200 B/row.
#define NINF (-__builtin_inff())
#define A2_FLUSH_ADV()                                                  \
    do {                                                                \
        float vx_ = dncur * acc.x + bf.x, vy_ = dncur * acc.y + bf.y;   \
        int gb_ = batch[n];                                             \
        if (gb_ != gcur) {                                              \
            long long pb_ = (long long)gcur * D_OUT + lane * 2;         \
            atomicMax(&pool[pb_], fmap(mx));                            \
            atomicMax(&pool[pb_ + 1], fmap(my));                        \
            gcur = gb_; mx = NINF; my = NINF;                           \
        }                                                               \
        mx = mx > vx_ ? mx : vx_; my = my > vy_ ? my : vy_;             \
        ++n;                                                            \
        nend = off[n + 1];                                              \
        dncur = dinv[n];                                                \
        acc = unpackbf2(hnext);                                         \
        int np_ = (n + 1 < N) ? (n + 1) : (N - 1);                      \
        hnext = H2[(long long)np_ * 50 + lane];                         \
    } while (0)

__global__ __launch_bounds__(256) void agg2pool_k(const unsigned* __restrict__ H2,
                                                  const int* __restrict__ off,
                                                  const int* __restrict__ csr,
                                                  const float* __restrict__ dinv,
                                                  const int* __restrict__ batch,
                                                  const float* __restrict__ b2,
                                                  unsigned* __restrict__ pool,
                                                  int N, int chunk) {
    int grp = blockIdx.x * 4 + (threadIdx.x >> 6);
    int lane = threadIdx.x & 63;
    if (lane >= 50) return;
    int n0 = grp * chunk;
    int n1 = n0 + chunk; if (n1 > N) n1 = N;
    if (n0 >= n1) return;
    float2 bf = ((const float2*)b2)[lane];
    float mx = NINF, my = NINF;
    int gcur = batch[n0];
    int n = n0;
    int i = off[n0];
    int eend = off[n1];
    int nend = off[n0 + 1];
    float dncur = dinv[n0];
    float2 acc = unpackbf2(H2[(long long)n0 * 50 + lane]);
    int np0 = (n0 + 1 < N) ? (n0 + 1) : (N - 1);
    unsigned hnext = H2[(long long)np0 * 50 + lane];
    while (i + 4 <= eend) {
        int s0 = csr[i], s1 = csr[i + 1], s2 = csr[i + 2], s3 = csr[i + 3];
        unsigned g0 = H2[(long long)s0 * 50 + lane];
        unsigned g1 = H2[(long long)s1 * 50 + lane];
        unsigned g2 = H2[(long long)s2 * 50 + lane];
        unsigned g3 = H2[(long long)s3 * 50 + lane];
        while (i >= nend) A2_FLUSH_ADV();
        { float2 f = unpackbf2(g0); acc.x += f.x; acc.y += f.y; }
        while (i + 1 >= nend) A2_FLUSH_ADV();
        { float2 f = unpackbf2(g1); acc.x += f.x; acc.y += f.y; }
        while (i + 2 >= nend) A2_FLUSH_ADV();
        { float2 f = unpackbf2(g2); acc.x += f.x; acc.y += f.y; }
        while (i + 3 >= nend) A2_FLUSH_ADV();
        { float2 f = unpackbf2(g3); acc.x += f.x; acc.y += f.y; }
        i += 4;
    }
    while (i < eend) {
        int s0 = csr[i];
        unsigned g0 = H2[(long long)s0 * 50 + lane];
        while (i >= nend) A2_FLUSH_ADV();
        { float2 f = unpackbf2(g0); acc.x += f.x; acc.y += f.y; }
        ++i;
    }
    for (;;) {  // trailing flushes
        float vx_ = dncur * acc.x + bf.x, vy_ = dncur * acc.y + bf.y;
        int gb_ = batch[n];
        if (gb_ != gcur) {
            long long pb_ = (long long)gcur * D_OUT + lane * 2;
            atomicMax(&pool[pb_], fmap(mx));
            atomicMax(&pool[pb_ + 1], fmap(my));
            gcur = gb_; mx = NINF; my = NINF;
        }
        mx = mx > vx_ ? mx : vx_; my = my > vy_ ? my : vy_;
        ++n;
        if (n >= n1) break;
        dncur = dinv[n];
        acc = unpackbf2(hnext);
        int np_ = (n + 1 < N) ? (n + 1) : (N - 1);
        hnext = H2[(long long)np_ * 50 + lane];
    }
    long long pb = (long long)gcur * D_OUT + lane * 2;
    atomicMax(&pool[pb], fmap(mx));
    atomicMax(&pool[pb + 1], fmap(my));
}

__global__ __launch_bounds__(256) void pool_final_k(const unsigned* __restrict__ pool,
                                                    float* __restrict__ out, int P) {
    int i = blockIdx.x * 256 + threadIdx.x;
    if (i < P) out[i] = funmap(pool[i]);
}

// ---------------- launch ----------------
extern "C" void kernel_launch(void* const* d_in, const int* in_sizes, int n_in,
                              void* d_out, int out_size, void* d_ws, size_t ws_size,
                              hipStream_t stream) {
    const float* X     = (const float*)d_in[0];
    const int*   eidx  = (const int*)d_in[1];
    const int*   batch = (const int*)d_in[2];
    const float* W1    = (const float*)d_in[4];
    // d_in[5] = b1: cancels inside batch_norm
    const float* gamma = (const float*)d_in[6];
    const float* beta  = (const float*)d_in[7];
    const float* W2    = (const float*)d_in[8];
    const float* b2    = (const float*)d_in[9];

    const int N = in_sizes[0] / D_HID;     // 200000
    const int E = in_sizes[1] / 2;         // 600000
    const int P = out_size;                // num_graphs * 100
    const int* src = eidx;
    const int* dst = eidx + E;

    // workspace layout
    char* p = (char*)d_ws;
    auto alloc = [&](size_t bytes) { char* q = p; p += (bytes + 255) & ~(size_t)255; return q; };
    int*      deg    = (int*)alloc((size_t)N * 4);
    int*      cursor = (int*)alloc((size_t)N * 4);
    int*      off    = (int*)alloc((size_t)(N + 1) * 4);
    int*      btot   = (int*)alloc(256 * 4);
    int*      csr    = (int*)alloc((size_t)E * 4);
    float*    dinv   = (float*)alloc((size_t)N * 4);
    float*    bnsum  = (float*)alloc(128 * 4);
    float*    bnsq   = (float*)alloc(128 * 4);
    float*    scale  = (float*)alloc(128 * 4);
    float*    shift  = (float*)alloc(128 * 4);
    unsigned* pool   = (unsigned*)alloc((size_t)P * 4);
    unsigned* A      = (unsigned*)alloc((size_t)N * 128 * 2);  // H' bf16 (then H2', stride 100)
    unsigned* B      = (unsigned*)alloc((size_t)N * 128 * 2);  // X1 bf16

    const int nb1 = (N + SCAN_EPB - 1) / SCAN_EPB;          // 196 <= 256
    const int initN = (N > P ? N : P);

    init_k<<<(initN + 255) / 256, 256, 0, stream>>>(deg, cursor, pool, bnsum, bnsq, N, P);
    deg_k<<<(E + 255) / 256, 256, 0, stream>>>(dst, deg, E);
    scan1_k<<<nb1, 256, 0, stream>>>(deg, off, btot, N);
    scan2_k<<<1, 256, 0, stream>>>(btot, nb1, off, N, E);
    scan3_dinv_k<<<(N + 255) / 256, 256, 0, stream>>>(off, btot, deg, dinv, N);
    fill_k<<<(E + 255) / 256, 256, 0, stream>>>(src, dst, off, cursor, csr, E);

    gemm1_k<<<(N + BM - 1) / BM, 256, 0, stream>>>(X, W1, dinv, A, N);

    const int nblk_agg = 2048;
    const int ngrp = nblk_agg * 4;                 // one 64-lane wave per group
    const int chunk = (N + ngrp - 1) / ngrp;       // 25
    agg1_k<<<nblk_agg, 256, 0, stream>>>(A, off, csr, dinv, B, bnsum, bnsq, N, chunk);
    bnfinal_k<<<1, 128, 0, stream>>>(bnsum, bnsq, gamma, beta, scale, shift, N);

    gemm2_k<<<(N + BM - 1) / BM, 256, 0, stream>>>(B, W2, scale, shift, dinv, A, N);

    agg2pool_k<<<nblk_agg, 256, 0, stream>>>(A, off, csr, dinv, batch, b2, pool, N, chunk);
    pool_final_k<<<(P + 255) / 256, 256, 0, stream>>>(pool, (float*)d_out, P);
}

// Round 6
// 313.112 us; speedup vs baseline: 2.1426x; 1.4852x over previous
//
#include <hip/hip_runtime.h>
#include <hip/hip_bf16.h>

#define D_HID 128
#define D_OUT 100
#define BN_EPS 1e-5f
#define XP 136              // padded LDS row (bf16 elems) -> 272 B: 16B-aligned, bank-stride 4
#define ROWB 272

typedef short bf16x8 __attribute__((ext_vector_type(8)));
typedef float f32x4 __attribute__((ext_vector_type(4)));

// ---------------- helpers ----------------
__device__ __forceinline__ unsigned fmap(float f) {
    unsigned u = __float_as_uint(f);
    return (u & 0x80000000u) ? ~u : (u | 0x80000000u);
}
__device__ __forceinline__ float funmap(unsigned u) {
    return __uint_as_float((u & 0x80000000u) ? (u ^ 0x80000000u) : ~u);
}
#define NEG_INF_MAPPED 0x007FFFFFu  // fmap(-inf)

__device__ __forceinline__ unsigned short f2bf(float f) {  // RNE f32->bf16
    unsigned u = __float_as_uint(f);
    return (unsigned short)((u + 0x7fffu + ((u >> 16) & 1u)) >> 16);
}
__device__ __forceinline__ unsigned packbf2(float x, float y) {
    return (unsigned)f2bf(x) | ((unsigned)f2bf(y) << 16);
}
__device__ __forceinline__ float2 unpackbf2(unsigned v) {
    float2 r;
    r.x = __uint_as_float(v << 16);
    r.y = __uint_as_float(v & 0xffff0000u);
    return r;
}

// ---------------- init ----------------
__global__ __launch_bounds__(256) void init_k(int* deg, int* cursor, unsigned* pool,
                                              float* bnsum, float* bnsq, int N, int P) {
    int i = blockIdx.x * 256 + threadIdx.x;
    if (i < N) { deg[i] = 0; cursor[i] = 0; }
    if (i < P) pool[i] = NEG_INF_MAPPED;
    if (i < 128) { bnsum[i] = 0.f; bnsq[i] = 0.f; }
}

__global__ __launch_bounds__(256) void deg_k(const int* __restrict__ dst, int* deg, int E) {
    int e = blockIdx.x * 256 + threadIdx.x;
    if (e < E) atomicAdd(&deg[dst[e]], 1);
}

// ---------------- exclusive scan over deg -> off (2-level) ----------------
#define SCAN_EPB 1024
__global__ __launch_bounds__(256) void scan1_k(const int* __restrict__ deg, int* __restrict__ off,
                                               int* __restrict__ btot, int N) {
    __shared__ int ts[256];
    int base = blockIdx.x * SCAN_EPB + threadIdx.x * 4;
    int v[4];
    int s = 0;
#pragma unroll
    for (int j = 0; j < 4; ++j) { int idx = base + j; v[j] = (idx < N) ? deg[idx] : 0; s += v[j]; }
    ts[threadIdx.x] = s;
    __syncthreads();
    for (int d = 1; d < 256; d <<= 1) {
        int t = (threadIdx.x >= d) ? ts[threadIdx.x - d] : 0;
        __syncthreads();
        ts[threadIdx.x] += t;
        __syncthreads();
    }
    int excl = ts[threadIdx.x] - s;
#pragma unroll
    for (int j = 0; j < 4; ++j) { int idx = base + j; if (idx < N) off[idx] = excl; excl += v[j]; }
    if (threadIdx.x == 255) btot[blockIdx.x] = ts[255];
}

__global__ __launch_bounds__(256) void scan2_k(int* btot, int nb, int* off, int N, int E) {
    __shared__ int ts[256];
    int v = (threadIdx.x < nb) ? btot[threadIdx.x] : 0;
    ts[threadIdx.x] = v;
    __syncthreads();
    for (int d = 1; d < 256; d <<= 1) {
        int t = (threadIdx.x >= d) ? ts[threadIdx.x - d] : 0;
        __syncthreads();
        ts[threadIdx.x] += t;
        __syncthreads();
    }
    if (threadIdx.x < nb) btot[threadIdx.x] = ts[threadIdx.x] - v;  // exclusive
    if (threadIdx.x == 0) off[N] = E;
}

__global__ __launch_bounds__(256) void scan3_dinv_k(int* off, const int* __restrict__ btot,
                                                    const int* __restrict__ deg,
                                                    float* __restrict__ dinv, int N) {
    int i = blockIdx.x * 256 + threadIdx.x;
    if (i < N) {
        off[i] += btot[i / SCAN_EPB];
        dinv[i] = rsqrtf((float)(1 + deg[i]));  // +1 self-loop
    }
}

__global__ __launch_bounds__(256) void fill_k(const int* __restrict__ src, const int* __restrict__ dst,
                                              const int* __restrict__ off, int* cursor,
                                              int* __restrict__ csr, int E) {
    int e = blockIdx.x * 256 + threadIdx.x;
    if (e < E) {
        int d = dst[e];
        int p = atomicAdd(&cursor[d], 1);
        csr[off[d] + p] = src[e];
    }
}

// ---------------- prep: transpose weights to bf16 [col][k] ----------------
__global__ __launch_bounds__(256) void prepW_k(const float* __restrict__ W1,
                                               const float* __restrict__ W2,
                                               unsigned short* __restrict__ W1t,
                                               unsigned short* __restrict__ W2t) {
    int t = blockIdx.x * 256 + threadIdx.x;
    if (t < 16384) { int n = t >> 7, k = t & 127; W1t[t] = f2bf(W1[k * 128 + n]); }
    if (t < 14336) { int c = t >> 7, k = t & 127; W2t[t] = (c < D_OUT) ? f2bf(W2[k * D_OUT + c]) : (unsigned short)0; }
}

// ---------------- GEMM1 (MFMA): H' = dinv .* bf16(X @ W1), bf16 out ----------------
// 64 rows/block, 4 waves x 16 rows, 8 col-tiles, K=128 (4 steps of 32).
__global__ __launch_bounds__(256) void gemm1_k(const float* __restrict__ X,
                                               const unsigned short* __restrict__ W1t,
                                               const float* __restrict__ dinv,
                                               unsigned* __restrict__ H, int N) {
    __shared__ char smem[64 * ROWB + 128 * ROWB];
    char* Xs = smem;                 // [64][XP] bf16; reused as Cs after compute
    char* Wt = smem + 64 * ROWB;     // [128][XP] bf16
    int tid = threadIdx.x;
    int row0 = blockIdx.x * 64;
    {   // stage Wt (2048 uint4, contiguous global)
        const uint4* Wg = (const uint4*)W1t;
#pragma unroll
        for (int i = 0; i < 8; ++i) {
            int idx = i * 256 + tid;
            uint4 u = Wg[idx];
            *(uint4*)(Wt + (idx >> 4) * ROWB + (idx & 15) * 16) = u;
        }
    }
    {   // stage Xs: f32 -> bf16
        const float4* Xg = (const float4*)X;
#pragma unroll
        for (int i = 0; i < 8; ++i) {
            int idx = i * 256 + tid;
            int r = idx >> 5, c4 = idx & 31;
            int grow = row0 + r; if (grow >= N) grow = N - 1;
            float4 v = Xg[(long long)grow * 32 + c4];
            uint2 o; o.x = packbf2(v.x, v.y); o.y = packbf2(v.z, v.w);
            *(uint2*)(Xs + r * ROWB + c4 * 8) = o;
        }
    }
    __syncthreads();
    int w = tid >> 6, l = tid & 63;
    int arow = w * 16 + (l & 15);
    int koff = (l >> 4) * 16;       // byte offset of this lane-group's K-slice
    f32x4 acc[8];
#pragma unroll
    for (int ct = 0; ct < 8; ++ct)
#pragma unroll
        for (int r = 0; r < 4; ++r) acc[ct][r] = 0.f;
#pragma unroll
    for (int ks = 0; ks < 4; ++ks) {
        int kb = ks * 64 + koff;
        bf16x8 a = *(const bf16x8*)(Xs + arow * ROWB + kb);
#pragma unroll
        for (int ct = 0; ct < 8; ++ct) {
            bf16x8 b = *(const bf16x8*)(Wt + (ct * 16 + (l & 15)) * ROWB + kb);
            acc[ct] = __builtin_amdgcn_mfma_f32_16x16x32_bf16(a, b, acc[ct], 0, 0, 0);
        }
    }
    __syncthreads();
    {   // scatter acc -> Cs (bf16, reuse Xs)   C: col=lane&15, row=(lane>>4)*4+reg
        int crow0 = w * 16 + (l >> 4) * 4;
        int ccol = l & 15;
#pragma unroll
        for (int ct = 0; ct < 8; ++ct)
#pragma unroll
            for (int r = 0; r < 4; ++r)
                *(unsigned short*)(Xs + (crow0 + r) * ROWB + (ct * 16 + ccol) * 2) = f2bf(acc[ct][r]);
    }
    __syncthreads();
    // flush coalesced: 64 rows x 64 uints, fold dinv
#pragma unroll
    for (int i = 0; i < 16; ++i) {
        int idx = i * 256 + tid;
        int r = idx >> 6, cu = idx & 63;
        int grow = row0 + r;
        if (grow < N) {
            float2 f = unpackbf2(*(unsigned*)(Xs + r * ROWB + cu * 4));
            float d = dinv[grow];
            H[(long long)grow * 64 + cu] = packbf2(f.x * d, f.y * d);
        }
    }
}

// ---------------- agg1: X1 = dinv .* (H' + sum_nbr H'), fused BN stats ----------------
#define A1_FLUSH_ADV()                                                  \
    do {                                                                \
        float ox = dncur * acc.x, oy = dncur * acc.y;                   \
        X1[(long long)n * 64 + lane] = packbf2(ox, oy);                 \
        bs.x += ox; bs.y += oy;                                         \
        bq.x += ox * ox; bq.y += oy * oy;                               \
        ++n;                                                            \
        nend = off[n + 1];                                              \
        dncur = dinv[n];                                                \
        acc = unpackbf2(hnext);                                         \
        int np_ = (n + 1 < N) ? (n + 1) : (N - 1);                      \
        hnext = H[(long long)np_ * 64 + lane];                          \
    } while (0)

__global__ __launch_bounds__(256) void agg1_k(const unsigned* __restrict__ H,
                                              const int* __restrict__ off,
                                              const int* __restrict__ csr,
                                              const float* __restrict__ dinv,
                                              unsigned* __restrict__ X1,
                                              float* bnsum, float* bnsq,
                                              int N, int chunk) {
    int grp = blockIdx.x * 4 + (threadIdx.x >> 6);
    int lane = threadIdx.x & 63;
    int n0 = grp * chunk;
    int n1 = n0 + chunk; if (n1 > N) n1 = N;
    float2 bs; bs.x = 0.f; bs.y = 0.f;
    float2 bq; bq.x = 0.f; bq.y = 0.f;
    if (n0 < n1) {
        int n = n0;
        int i = off[n0];
        int eend = off[n1];
        int nend = off[n0 + 1];
        float dncur = dinv[n0];
        float2 acc = unpackbf2(H[(long long)n0 * 64 + lane]);
        int np0 = (n0 + 1 < N) ? (n0 + 1) : (N - 1);
        unsigned hnext = H[(long long)np0 * 64 + lane];
        while (i + 4 <= eend) {
            int s0 = csr[i], s1 = csr[i + 1], s2 = csr[i + 2], s3 = csr[i + 3];
            unsigned g0 = H[(long long)s0 * 64 + lane];
            unsigned g1 = H[(long long)s1 * 64 + lane];
            unsigned g2 = H[(long long)s2 * 64 + lane];
            unsigned g3 = H[(long long)s3 * 64 + lane];
            while (i >= nend) A1_FLUSH_ADV();
            { float2 f = unpackbf2(g0); acc.x += f.x; acc.y += f.y; }
            while (i + 1 >= nend) A1_FLUSH_ADV();
            { float2 f = unpackbf2(g1); acc.x += f.x; acc.y += f.y; }
            while (i + 2 >= nend) A1_FLUSH_ADV();
            { float2 f = unpackbf2(g2); acc.x += f.x; acc.y += f.y; }
            while (i + 3 >= nend) A1_FLUSH_ADV();
            { float2 f = unpackbf2(g3); acc.x += f.x; acc.y += f.y; }
            i += 4;
        }
        while (i < eend) {
            int s0 = csr[i];
            unsigned g0 = H[(long long)s0 * 64 + lane];
            while (i >= nend) A1_FLUSH_ADV();
            { float2 f = unpackbf2(g0); acc.x += f.x; acc.y += f.y; }
            ++i;
        }
        for (;;) {  // trailing flushes
            float ox = dncur * acc.x, oy = dncur * acc.y;
            X1[(long long)n * 64 + lane] = packbf2(ox, oy);
            bs.x += ox; bs.y += oy;
            bq.x += ox * ox; bq.y += oy * oy;
            ++n;
            if (n >= n1) break;
            dncur = dinv[n];
            acc = unpackbf2(hnext);
            int np_ = (n + 1 < N) ? (n + 1) : (N - 1);
            hnext = H[(long long)np_ * 64 + lane];
        }
    }
    __shared__ float2 ls[256], lq[256];
    ls[threadIdx.x] = bs; lq[threadIdx.x] = bq;
    __syncthreads();
    if (threadIdx.x < 64) {
        float2 s = ls[threadIdx.x], q = lq[threadIdx.x];
#pragma unroll
        for (int j = 64; j < 256; j += 64) {
            float2 a = ls[threadIdx.x + j], b = lq[threadIdx.x + j];
            s.x += a.x; s.y += a.y; q.x += b.x; q.y += b.y;
        }
        atomicAdd(&bnsum[threadIdx.x * 2 + 0], s.x);
        atomicAdd(&bnsum[threadIdx.x * 2 + 1], s.y);
        atomicAdd(&bnsq[threadIdx.x * 2 + 0], q.x);
        atomicAdd(&bnsq[threadIdx.x * 2 + 1], q.y);
    }
}

__global__ __launch_bounds__(128) void bnfinal_k(const float* bnsum, const float* bnsq,
                                                 const float* __restrict__ gamma,
                                                 const float* __restrict__ beta,
                                                 float* scale, float* shift, int N) {
    int c = threadIdx.x;
    float mu = bnsum[c] / (float)N;
    float var = bnsq[c] / (float)N - mu * mu;
    var = var > 0.f ? var : 0.f;
    float sc = gamma[c] * rsqrtf(var + BN_EPS);
    scale[c] = sc;
    shift[c] = beta[c] - mu * sc;
}

// ---------------- GEMM2 (MFMA): H2' = dinv .* bf16(relu(BN(X1)) @ W2) ----------------
// 64 rows/block, 7 col-tiles (112 cols, 100 real).
__global__ __launch_bounds__(256) void gemm2_k(const unsigned* __restrict__ X1,
                                               const unsigned short* __restrict__ W2t,
                                               const float* __restrict__ scale,
                                               const float* __restrict__ shift,
                                               const float* __restrict__ dinv,
                                               unsigned* __restrict__ H2, int N) {
    __shared__ char smem[64 * ROWB + 112 * ROWB];
    __shared__ float scs[128], shs[128];
    char* Xs = smem;                 // [64][XP] bf16; reused as Cs
    char* Wt = smem + 64 * ROWB;     // [112][XP] bf16
    int tid = threadIdx.x;
    int row0 = blockIdx.x * 64;
    if (tid < 128) { scs[tid] = scale[tid]; shs[tid] = shift[tid]; }
    {   // stage Wt2 (1792 uint4)
        const uint4* Wg = (const uint4*)W2t;
#pragma unroll
        for (int i = 0; i < 7; ++i) {
            int idx = i * 256 + tid;
            uint4 u = Wg[idx];
            *(uint4*)(Wt + (idx >> 4) * ROWB + (idx & 15) * 16) = u;
        }
    }
    __syncthreads();
    {   // stage Xs: bf16 -> BN+relu -> bf16
        const uint4* Xg = (const uint4*)X1;
#pragma unroll
        for (int i = 0; i < 4; ++i) {
            int idx = i * 256 + tid;
            int r = idx >> 4, kc = idx & 15;
            int grow = row0 + r; if (grow >= N) grow = N - 1;
            uint4 u = Xg[(long long)grow * 16 + kc];
            uint4 o;
#pragma unroll
            for (int jj = 0; jj < 4; ++jj) {
                float2 f = unpackbf2((&u.x)[jj]);
                int k = kc * 8 + jj * 2;
                float v0 = f.x * scs[k] + shs[k];
                float v1 = f.y * scs[k + 1] + shs[k + 1];
                (&o.x)[jj] = packbf2(v0 > 0.f ? v0 : 0.f, v1 > 0.f ? v1 : 0.f);
            }
            *(uint4*)(Xs + r * ROWB + kc * 16) = o;
        }
    }
    __syncthreads();
    int w = tid >> 6, l = tid & 63;
    int arow = w * 16 + (l & 15);
    int koff = (l >> 4) * 16;
    f32x4 acc[7];
#pragma unroll
    for (int ct = 0; ct < 7; ++ct)
#pragma unroll
        for (int r = 0; r < 4; ++r) acc[ct][r] = 0.f;
#pragma unroll
    for (int ks = 0; ks < 4; ++ks) {
        int kb = ks * 64 + koff;
        bf16x8 a = *(const bf16x8*)(Xs + arow * ROWB + kb);
#pragma unroll
        for (int ct = 0; ct < 7; ++ct) {
            bf16x8 b = *(const bf16x8*)(Wt + (ct * 16 + (l & 15)) * ROWB + kb);
            acc[ct] = __builtin_amdgcn_mfma_f32_16x16x32_bf16(a, b, acc[ct], 0, 0, 0);
        }
    }
    __syncthreads();
    {   // scatter acc -> Cs
        int crow0 = w * 16 + (l >> 4) * 4;
        int ccol = l & 15;
#pragma unroll
        for (int ct = 0; ct < 7; ++ct)
#pragma unroll
            for (int r = 0; r < 4; ++r)
                *(unsigned short*)(Xs + (crow0 + r) * ROWB + (ct * 16 + ccol) * 2) = f2bf(acc[ct][r]);
    }
    __syncthreads();
    // flush: 64 rows x 50 uints (cols 0..99), fold dinv
#pragma unroll
    for (int i = 0; i < 13; ++i) {
        int idx = i * 256 + tid;
        if (idx < 3200) {
            int r = idx / 50, cu = idx - r * 50;
            int grow = row0 + r;
            if (grow < N) {
                float2 f = unpackbf2(*(unsigned*)(Xs + r * ROWB + cu * 4));
                float d = dinv[grow];
                H2[(long long)grow * 50 + cu] = packbf2(f.x * d, f.y * d);
            }
        }
    }
}

// ---------------- agg2 + bias + segment_max pool (batch sorted) ----------------
#define NINF (-__builtin_inff())
#define A2_FLUSH_ADV()                                                  \
    do {                                                                \
        float vx_ = dncur * acc.x + bf.x, vy_ = dncur * acc.y + bf.y;   \
        int gb_ = batch[n];                                             \
        if (gb_ != gcur) {                                              \
            long long pb_ = (long long)gcur * D_OUT + lane * 2;         \
            atomicMax(&pool[pb_], fmap(mx));                            \
            atomicMax(&pool[pb_ + 1], fmap(my));                        \
            gcur = gb_; mx = NINF; my = NINF;                           \
        }                                                               \
        mx = mx > vx_ ? mx : vx_; my = my > vy_ ? my : vy_;             \
        ++n;                                                            \
        nend = off[n + 1];                                              \
        dncur = dinv[n];                                                \
        acc = unpackbf2(hnext);                                         \
        int np_ = (n + 1 < N) ? (n + 1) : (N - 1);                      \
        hnext = H2[(long long)np_ * 50 + lane];                         \
    } while (0)

__global__ __launch_bounds__(256) void agg2pool_k(const unsigned* __restrict__ H2,
                                                  const int* __restrict__ off,
                                                  const int* __restrict__ csr,
                                                  const float* __restrict__ dinv,
                                                  const int* __restrict__ batch,
                                                  const float* __restrict__ b2,
                                                  unsigned* __restrict__ pool,
                                                  int N, int chunk) {
    int grp = blockIdx.x * 4 + (threadIdx.x >> 6);
    int lane = threadIdx.x & 63;
    if (lane >= 50) return;
    int n0 = grp * chunk;
    int n1 = n0 + chunk; if (n1 > N) n1 = N;
    if (n0 >= n1) return;
    float2 bf = ((const float2*)b2)[lane];
    float mx = NINF, my = NINF;
    int gcur = batch[n0];
    int n = n0;
    int i = off[n0];
    int eend = off[n1];
    int nend = off[n0 + 1];
    float dncur = dinv[n0];
    float2 acc = unpackbf2(H2[(long long)n0 * 50 + lane]);
    int np0 = (n0 + 1 < N) ? (n0 + 1) : (N - 1);
    unsigned hnext = H2[(long long)np0 * 50 + lane];
    while (i + 4 <= eend) {
        int s0 = csr[i], s1 = csr[i + 1], s2 = csr[i + 2], s3 = csr[i + 3];
        unsigned g0 = H2[(long long)s0 * 50 + lane];
        unsigned g1 = H2[(long long)s1 * 50 + lane];
        unsigned g2 = H2[(long long)s2 * 50 + lane];
        unsigned g3 = H2[(long long)s3 * 50 + lane];
        while (i >= nend) A2_FLUSH_ADV();
        { float2 f = unpackbf2(g0); acc.x += f.x; acc.y += f.y; }
        while (i + 1 >= nend) A2_FLUSH_ADV();
        { float2 f = unpackbf2(g1); acc.x += f.x; acc.y += f.y; }
        while (i + 2 >= nend) A2_FLUSH_ADV();
        { float2 f = unpackbf2(g2); acc.x += f.x; acc.y += f.y; }
        while (i + 3 >= nend) A2_FLUSH_ADV();
        { float2 f = unpackbf2(g3); acc.x += f.x; acc.y += f.y; }
        i += 4;
    }
    while (i < eend) {
        int s0 = csr[i];
        unsigned g0 = H2[(long long)s0 * 50 + lane];
        while (i >= nend) A2_FLUSH_ADV();
        { float2 f = unpackbf2(g0); acc.x += f.x; acc.y += f.y; }
        ++i;
    }
    for (;;) {  // trailing flushes
        float vx_ = dncur * acc.x + bf.x, vy_ = dncur * acc.y + bf.y;
        int gb_ = batch[n];
        if (gb_ != gcur) {
            long long pb_ = (long long)gcur * D_OUT + lane * 2;
            atomicMax(&pool[pb_], fmap(mx));
            atomicMax(&pool[pb_ + 1], fmap(my));
            gcur = gb_; mx = NINF; my = NINF;
        }
        mx = mx > vx_ ? mx : vx_; my = my > vy_ ? my : vy_;
        ++n;
        if (n >= n1) break;
        dncur = dinv[n];
        acc = unpackbf2(hnext);
        int np_ = (n + 1 < N) ? (n + 1) : (N - 1);
        hnext = H2[(long long)np_ * 50 + lane];
    }
    long long pb = (long long)gcur * D_OUT + lane * 2;
    atomicMax(&pool[pb], fmap(mx));
    atomicMax(&pool[pb + 1], fmap(my));
}

__global__ __launch_bounds__(256) void pool_final_k(const unsigned* __restrict__ pool,
                                                    float* __restrict__ out, int P) {
    int i = blockIdx.x * 256 + threadIdx.x;
    if (i < P) out[i] = funmap(pool[i]);
}

// ---------------- launch ----------------
extern "C" void kernel_launch(void* const* d_in, const int* in_sizes, int n_in,
                              void* d_out, int out_size, void* d_ws, size_t ws_size,
                              hipStream_t stream) {
    const float* X     = (const float*)d_in[0];
    const int*   eidx  = (const int*)d_in[1];
    const int*   batch = (const int*)d_in[2];
    const float* W1    = (const float*)d_in[4];
    // d_in[5] = b1: cancels inside batch_norm
    const float* gamma = (const float*)d_in[6];
    const float* beta  = (const float*)d_in[7];
    const float* W2    = (const float*)d_in[8];
    const float* b2    = (const float*)d_in[9];

    const int N = in_sizes[0] / D_HID;     // 200000
    const int E = in_sizes[1] / 2;         // 600000
    const int P = out_size;                // num_graphs * 100
    const int* src = eidx;
    const int* dst = eidx + E;

    // workspace layout
    char* p = (char*)d_ws;
    auto alloc = [&](size_t bytes) { char* q = p; p += (bytes + 255) & ~(size_t)255; return q; };
    int*      deg    = (int*)alloc((size_t)N * 4);
    int*      cursor = (int*)alloc((size_t)N * 4);
    int*      off    = (int*)alloc((size_t)(N + 1) * 4);
    int*      btot   = (int*)alloc(256 * 4);
    int*      csr    = (int*)alloc((size_t)E * 4);
    float*    dinv   = (float*)alloc((size_t)N * 4);
    float*    bnsum  = (float*)alloc(128 * 4);
    float*    bnsq   = (float*)alloc(128 * 4);
    float*    scale  = (float*)alloc(128 * 4);
    float*    shift  = (float*)alloc(128 * 4);
    unsigned short* W1t = (unsigned short*)alloc(16384 * 2);
    unsigned short* W2t = (unsigned short*)alloc(14336 * 2);
    unsigned* pool   = (unsigned*)alloc((size_t)P * 4);
    unsigned* A      = (unsigned*)alloc((size_t)N * 128 * 2);  // H' bf16 (then H2', stride 100)
    unsigned* B      = (unsigned*)alloc((size_t)N * 128 * 2);  // X1 bf16

    const int nb1 = (N + SCAN_EPB - 1) / SCAN_EPB;          // 196 <= 256
    const int initN = (N > P ? N : P);

    init_k<<<(initN + 255) / 256, 256, 0, stream>>>(deg, cursor, pool, bnsum, bnsq, N, P);
    deg_k<<<(E + 255) / 256, 256, 0, stream>>>(dst, deg, E);
    scan1_k<<<nb1, 256, 0, stream>>>(deg, off, btot, N);
    scan2_k<<<1, 256, 0, stream>>>(btot, nb1, off, N, E);
    scan3_dinv_k<<<(N + 255) / 256, 256, 0, stream>>>(off, btot, deg, dinv, N);
    fill_k<<<(E + 255) / 256, 256, 0, stream>>>(src, dst, off, cursor, csr, E);
    prepW_k<<<64, 256, 0, stream>>>(W1, W2, W1t, W2t);

    const int nblk_g = (N + 63) / 64;      // 3125
    gemm1_k<<<nblk_g, 256, 0, stream>>>(X, W1t, dinv, A, N);

    const int nblk_agg = 2048;
    const int ngrp = nblk_agg * 4;                 // one 64-lane wave per group
    const int chunk = (N + ngrp - 1) / ngrp;       // 25
    agg1_k<<<nblk_agg, 256, 0, stream>>>(A, off, csr, dinv, B, bnsum, bnsq, N, chunk);
    bnfinal_k<<<1, 128, 0, stream>>>(bnsum, bnsq, gamma, beta, scale, shift, N);

    gemm2_k<<<nblk_g, 256, 0, stream>>>(B, W2t, scale, shift, dinv, A, N);

    agg2pool_k<<<nblk_agg, 256, 0, stream>>>(A, off, csr, dinv, batch, b2, pool, N, chunk);
    pool_final_k<<<(P + 255) / 256, 256, 0, stream>>>(pool, (float*)d_out, P);
}